// Round 2
// baseline (838.359 us; speedup 1.0000x reference)
//
#include <hip/hip_runtime.h>
#include <hip/hip_bf16.h>
#include <stdint.h>

#define N_TOK 4096   // B*S
#define KF    8192   // IN_F
#define NF    8192   // OUT_F

#define BM 256
#define BN 256
#define NT (KF / 64)    // 128 K-tiles of 64
#define NKH (KF / 32)   // 256 K-half panels of 32

typedef __attribute__((ext_vector_type(8))) short short8;
typedef __attribute__((ext_vector_type(4))) float f32x4;

#define GLOBAL_P(p) ((const __attribute__((address_space(1))) void*)(p))
#define LDS_P(p)    ((__attribute__((address_space(3))) void*)(p))

// ---------- pass 1: int8-quantize activations, store as bf16 (exact) ----------
__global__ void quant_x(const float* __restrict__ x, const float* __restrict__ scale_p,
                        uint16_t* __restrict__ a) {
    const float s = *scale_p;
    const int n8 = N_TOK * KF / 8;
    const int stride = gridDim.x * blockDim.x;
    for (int i = blockIdx.x * blockDim.x + threadIdx.x; i < n8; i += stride) {
        const float4* xp = (const float4*)(x + (size_t)i * 8);
        float4 v0 = xp[0], v1 = xp[1];
        float q[8] = {v0.x, v0.y, v0.z, v0.w, v1.x, v1.y, v1.z, v1.w};
        union { uint16_t u16[8]; short8 v; } o;
        #pragma unroll
        for (int j = 0; j < 8; ++j) {
            float t = rintf(q[j] / s);
            t = fminf(fmaxf(t, -128.f), 127.f);
            union { float f; uint32_t u; } cv; cv.f = t;
            o.u16[j] = (uint16_t)(cv.u >> 16);
        }
        *(short8*)(a + (size_t)i * 8) = o.v;
    }
}

// ---------- pass 2: unpack nibbles + signs -> bf16 weights (exact powers of 2) ----------
__global__ void dequant_w(const int* __restrict__ packed, const int* __restrict__ signs,
                          const int* __restrict__ minexp_p, uint16_t* __restrict__ w) {
    const int me = *minexp_p;
    const int ebase = (me + 127) << 7;
    const int n4 = NF * (KF / 2) / 4;
    const int stride = gridDim.x * blockDim.x;
    for (int i = blockIdx.x * blockDim.x + threadIdx.x; i < n4; i += stride) {
        int4 p  = ((const int4*)packed)[i];
        int4 s0 = ((const int4*)signs)[(size_t)i * 2];
        int4 s1 = ((const int4*)signs)[(size_t)i * 2 + 1];
        int pw[4] = {p.x, p.y, p.z, p.w};
        int sg[8] = {s0.x, s0.y, s0.z, s0.w, s1.x, s1.y, s1.z, s1.w};
        union { uint16_t u16[8]; short8 v; } o;
        #pragma unroll
        for (int j = 0; j < 4; ++j) {
            int lo = pw[j] & 0xF, hi = (pw[j] >> 4) & 0xF;
            o.u16[2 * j]     = (uint16_t)((ebase + (lo << 7)) | (sg[2 * j]     < 0 ? 0x8000 : 0));
            o.u16[2 * j + 1] = (uint16_t)((ebase + (hi << 7)) | (sg[2 * j + 1] < 0 ? 0x8000 : 0));
        }
        *(short8*)(w + (size_t)i * 8) = o.v;
    }
}

// ---------- pass 3: 256x256-tile 8-phase bf16 GEMM, K-half ring, counted vmcnt ----------
// out[M,N] = A[M,K] * W[N,K]^T * s + bias
#define BARRIER()  asm volatile("s_barrier" ::: "memory")
#define WAITLGKM() asm volatile("s_waitcnt lgkmcnt(0)" ::: "memory")
#define WAITVM8()  asm volatile("s_waitcnt vmcnt(8)" ::: "memory")
#define WAITVM4()  asm volatile("s_waitcnt vmcnt(4)" ::: "memory")
#define WAITVM0()  asm volatile("s_waitcnt vmcnt(0)" ::: "memory")

__global__ __launch_bounds__(512, 2) void gemm_bt(
        const uint16_t* __restrict__ A, const uint16_t* __restrict__ W,
        const float* __restrict__ bias, const float* __restrict__ scale_p,
        float* __restrict__ out) {
    // 4-slot K-half ring per operand: slot = 256 rows x 32 cols bf16 = 16 KiB
    __shared__ uint16_t ldsA[4 * 256 * 32];   // 64 KiB
    __shared__ uint16_t ldsB[4 * 256 * 32];   // 64 KiB

    const int tid  = threadIdx.x;
    const int wid  = tid >> 6, lane = tid & 63;
    const int wr = wid >> 2, wc = wid & 3;         // 2x4 wave grid; wave tile 128x64
    const int rlane = lane & 15, kgrp = lane >> 4;

    // XCD-aware swizzle (512 blocks, 512 % 8 == 0)
    const int bid = blockIdx.x;
    const int swz = (bid & 7) * 64 + (bid >> 3);
    const int bx = swz & 31;                       // N tile
    const int by = swz >> 5;                       // M tile
    const int rowA0 = by * BM;
    const int colB0 = bx * BN;

    // ---- staging addresses: LDS physical o = (q*512+tid)*16 (linear for gload_lds);
    //      logical = o ^ st_16x32 swizzle; decode to (row, colbyte) ----
    const int o0 = tid * 16, o1 = (512 + tid) * 16;
    const int l0 = o0 ^ (((o0 >> 9) & 1) << 5);
    const int l1 = o1 ^ (((o1 >> 9) & 1) << 5);
    const char* gA0 = (const char*)A + ((size_t)(rowA0 + (l0 >> 6)) * KF) * 2 + (l0 & 63);
    const char* gA1 = (const char*)A + ((size_t)(rowA0 + (l1 >> 6)) * KF) * 2 + (l1 & 63);
    const char* gB0 = (const char*)W + ((size_t)(colB0 + (l0 >> 6)) * KF) * 2 + (l0 & 63);
    const char* gB1 = (const char*)W + ((size_t)(colB0 + (l1 >> 6)) * KF) * 2 + (l1 & 63);
    const int ldst0 = wid * 1024;                  // wave-uniform LDS dest, q=0
    const int ldst1 = 8192 + wid * 1024;           // q=1

    // ---- fragment read offsets (swizzled), all later indexing compile-time ----
    int aoff[8], boff[4];
    #pragma unroll
    for (int i = 0; i < 8; ++i) {
        int row = wr * 128 + i * 16 + rlane;
        int o = row * 64 + kgrp * 16;
        aoff[i] = o ^ (((o >> 9) & 1) << 5);
    }
    #pragma unroll
    for (int n = 0; n < 4; ++n) {
        int row = wc * 64 + n * 16 + rlane;
        int o = row * 64 + kgrp * 16;
        boff[n] = o ^ (((o >> 9) & 1) << 5);
    }

#define STAGE_A(j) do { \
    char* b_ = (char*)ldsA + ((j) & 3) * 16384; \
    __builtin_amdgcn_global_load_lds(GLOBAL_P(gA0 + (size_t)(j) * 64), LDS_P(b_ + ldst0), 16, 0, 0); \
    __builtin_amdgcn_global_load_lds(GLOBAL_P(gA1 + (size_t)(j) * 64), LDS_P(b_ + ldst1), 16, 0, 0); \
} while (0)
#define STAGE_B(j) do { \
    char* b_ = (char*)ldsB + ((j) & 3) * 16384; \
    __builtin_amdgcn_global_load_lds(GLOBAL_P(gB0 + (size_t)(j) * 64), LDS_P(b_ + ldst0), 16, 0, 0); \
    __builtin_amdgcn_global_load_lds(GLOBAL_P(gB1 + (size_t)(j) * 64), LDS_P(b_ + ldst1), 16, 0, 0); \
} while (0)
#define LDA(h, slot) do { \
    const char* pa_ = (const char*)ldsA + (slot) * 16384; \
    _Pragma("unroll") for (int mm_ = 0; mm_ < 4; ++mm_) \
        afr[mm_] = *(const short8*)(pa_ + aoff[(h) * 4 + mm_]); \
} while (0)
#define LDB(slot) do { \
    const char* pb_ = (const char*)ldsB + (slot) * 16384; \
    _Pragma("unroll") for (int nn_ = 0; nn_ < 4; ++nn_) \
        bfr[nn_] = *(const short8*)(pb_ + boff[nn_]); \
} while (0)
#define MFMA_HALF(h) do { \
    __builtin_amdgcn_s_setprio(1); \
    _Pragma("unroll") for (int mm_ = 0; mm_ < 4; ++mm_) \
        _Pragma("unroll") for (int nn_ = 0; nn_ < 4; ++nn_) \
            acc[(h) * 4 + mm_][nn_] = __builtin_amdgcn_mfma_f32_16x16x32_bf16( \
                afr[mm_], bfr[nn_], acc[(h) * 4 + mm_][nn_], 0, 0, 0); \
    __builtin_amdgcn_s_setprio(0); \
} while (0)

    f32x4 acc[8][4] = {};
    short8 afr[4], bfr[4];

    // ---- prologue: prime 3 K-half panel pairs (Kh0..Kh2), keep 4 units in flight ----
    STAGE_A(0); STAGE_B(0);
    STAGE_A(1); STAGE_B(1);
    STAGE_A(2); STAGE_B(2);
    WAITVM8();          // Kh0 A,B landed
    BARRIER();

    // ---- main loop: tiles 0..126 (tile 127 peeled) ----
    for (int t = 0; t < NT - 1; ++t) {
        const int j0 = 2 * t;
        const int s0 = j0 & 3, s1 = (j0 + 1) & 3;
        const bool g3 = (j0 + 3) < NKH;    // stage Kh(j0+3)?  (false only never here; t<=126 -> 255 ok)
        const bool g4 = (j0 + 4) < NKH;    // stage Kh(j0+4)?  (false at t==126)

        // phase 0: C-half 0 x Kh(j0)
        LDA(0, s0); LDB(s0);
        if (g3) STAGE_A(j0 + 3);
        BARRIER(); WAITLGKM();
        MFMA_HALF(0);
        BARRIER();
        // phase 1: C-half 1 x Kh(j0)
        LDA(1, s0);
        if (g3) STAGE_B(j0 + 3);
        BARRIER(); WAITLGKM();
        MFMA_HALF(1);
        WAITVM8();      // Kh(j0+1) A,B landed
        BARRIER();
        // phase 2: C-half 0 x Kh(j0+1)
        LDA(0, s1); LDB(s1);
        if (g4) STAGE_A(j0 + 4);
        BARRIER(); WAITLGKM();
        MFMA_HALF(0);
        BARRIER();
        // phase 3: C-half 1 x Kh(j0+1)
        LDA(1, s1);
        if (g4) STAGE_B(j0 + 4);
        BARRIER(); WAITLGKM();
        MFMA_HALF(1);
        if (t == NT - 2) { WAITVM4(); } else { WAITVM8(); }   // next tile's Kh pair landed
        BARRIER();
    }

    // ---- peeled last tile (t = 127, j0 = 254, slots 2/3, no stages) ----
    {
        LDA(0, 2); LDB(2);
        BARRIER(); WAITLGKM();
        MFMA_HALF(0);
        BARRIER();
        LDA(1, 2);
        BARRIER(); WAITLGKM();
        MFMA_HALF(1);
        WAITVM0();      // Kh255 landed
        BARRIER();
        LDA(0, 3); LDB(3);
        BARRIER(); WAITLGKM();
        MFMA_HALF(0);
        BARRIER();
        LDA(1, 3);
        WAITLGKM();
        MFMA_HALF(1);
    }

    // ---- epilogue: C/D layout col = lane&15, row = (lane>>4)*4 + r ----
    const float s = *scale_p;
    const int colbase = colB0 + wc * 64 + rlane;
    const int rowbase = rowA0 + wr * 128 + kgrp * 4;
    #pragma unroll
    for (int n = 0; n < 4; ++n) {
        const float bv = bias[colbase + n * 16];
        #pragma unroll
        for (int mf = 0; mf < 8; ++mf) {
            #pragma unroll
            for (int r = 0; r < 4; ++r)
                out[(size_t)(rowbase + mf * 16 + r) * NF + colbase + n * 16] = acc[mf][n][r] * s + bv;
        }
    }
#undef STAGE_A
#undef STAGE_B
#undef LDA
#undef LDB
#undef MFMA_HALF
}

extern "C" void kernel_launch(void* const* d_in, const int* in_sizes, int n_in,
                              void* d_out, int out_size, void* d_ws, size_t ws_size,
                              hipStream_t stream) {
    const float* x      = (const float*)d_in[0];
    const int*   packed = (const int*)d_in[1];
    const int*   signs  = (const int*)d_in[2];
    const float* bias   = (const float*)d_in[3];
    const float* scale  = (const float*)d_in[4];
    const int*   minexp = (const int*)d_in[5];
    float* out = (float*)d_out;

    uint16_t* A = (uint16_t*)d_ws;                                       // 64 MiB
    uint16_t* W = (uint16_t*)((char*)d_ws + (size_t)N_TOK * KF * 2);     // 128 MiB

    quant_x<<<2048, 256, 0, stream>>>(x, scale, A);
    dequant_w<<<2048, 256, 0, stream>>>(packed, signs, minexp, W);
    gemm_bt<<<(N_TOK / BM) * (NF / BN), 512, 0, stream>>>(A, W, bias, scale, out);
}

// Round 3
// 677.778 us; speedup vs baseline: 1.2369x; 1.2369x over previous
//
#include <hip/hip_runtime.h>
#include <hip/hip_bf16.h>
#include <stdint.h>

#define N_TOK 4096   // B*S
#define KF    8192   // IN_F
#define NF    8192   // OUT_F

#define BM 256
#define BN 256
#define NT (KF / 64)    // 128 K-tiles of 64
#define NKH (KF / 32)   // 256 K-half panels of 32

typedef __attribute__((ext_vector_type(8))) short short8;
typedef __attribute__((ext_vector_type(4))) float f32x4;

#define GLOBAL_P(p) ((const __attribute__((address_space(1))) void*)(p))
#define LDS_P(p)    ((__attribute__((address_space(3))) void*)(p))

// ---------- pass 1: int8-quantize activations, store as bf16 (exact) ----------
__global__ void quant_x(const float* __restrict__ x, const float* __restrict__ scale_p,
                        uint16_t* __restrict__ a) {
    const float s = *scale_p;
    const int n8 = N_TOK * KF / 8;
    const int stride = gridDim.x * blockDim.x;
    for (int i = blockIdx.x * blockDim.x + threadIdx.x; i < n8; i += stride) {
        const float4* xp = (const float4*)(x + (size_t)i * 8);
        float4 v0 = xp[0], v1 = xp[1];
        float q[8] = {v0.x, v0.y, v0.z, v0.w, v1.x, v1.y, v1.z, v1.w};
        union { uint16_t u16[8]; short8 v; } o;
        #pragma unroll
        for (int j = 0; j < 8; ++j) {
            float t = rintf(q[j] / s);
            t = fminf(fmaxf(t, -128.f), 127.f);
            union { float f; uint32_t u; } cv; cv.f = t;
            o.u16[j] = (uint16_t)(cv.u >> 16);
        }
        *(short8*)(a + (size_t)i * 8) = o.v;
    }
}

// ---------- pass 2: unpack nibbles + signs -> bf16 weights (exact powers of 2) ----------
__global__ void dequant_w(const int* __restrict__ packed, const int* __restrict__ signs,
                          const int* __restrict__ minexp_p, uint16_t* __restrict__ w) {
    const int me = *minexp_p;
    const int ebase = (me + 127) << 7;
    const int n4 = NF * (KF / 2) / 4;
    const int stride = gridDim.x * blockDim.x;
    for (int i = blockIdx.x * blockDim.x + threadIdx.x; i < n4; i += stride) {
        int4 p  = ((const int4*)packed)[i];
        int4 s0 = ((const int4*)signs)[(size_t)i * 2];
        int4 s1 = ((const int4*)signs)[(size_t)i * 2 + 1];
        int pw[4] = {p.x, p.y, p.z, p.w};
        int sg[8] = {s0.x, s0.y, s0.z, s0.w, s1.x, s1.y, s1.z, s1.w};
        union { uint16_t u16[8]; short8 v; } o;
        #pragma unroll
        for (int j = 0; j < 4; ++j) {
            int lo = pw[j] & 0xF, hi = (pw[j] >> 4) & 0xF;
            o.u16[2 * j]     = (uint16_t)((ebase + (lo << 7)) | (sg[2 * j]     < 0 ? 0x8000 : 0));
            o.u16[2 * j + 1] = (uint16_t)((ebase + (hi << 7)) | (sg[2 * j + 1] < 0 ? 0x8000 : 0));
        }
        *(short8*)(w + (size_t)i * 8) = o.v;
    }
}

// ---------- pass 3: 256x256-tile 8-phase bf16 GEMM, K-half ring, counted vmcnt ----------
// out[M,N] = A[M,K] * W[N,K]^T * s + bias
#define BARRIER()  asm volatile("s_barrier" ::: "memory")
#define WAITLGKM() asm volatile("s_waitcnt lgkmcnt(0)" ::: "memory")
#define WAITVM8()  asm volatile("s_waitcnt vmcnt(8)" ::: "memory")
#define WAITVM4()  asm volatile("s_waitcnt vmcnt(4)" ::: "memory")
#define WAITVM0()  asm volatile("s_waitcnt vmcnt(0)" ::: "memory")

__global__ __launch_bounds__(512, 2) void gemm_bt(
        const uint16_t* __restrict__ A, const uint16_t* __restrict__ W,
        const float* __restrict__ bias, const float* __restrict__ scale_p,
        float* __restrict__ out) {
    // 4-slot K-half ring per operand: slot = 256 rows x 32 cols bf16 = 16 KiB
    __shared__ uint16_t ldsA[4 * 256 * 32];   // 64 KiB
    __shared__ uint16_t ldsB[4 * 256 * 32];   // 64 KiB

    const int tid  = threadIdx.x;
    const int wid  = tid >> 6, lane = tid & 63;
    const int wr = wid >> 2, wc = wid & 3;         // 2x4 wave grid; wave tile 128x64
    const int rlane = lane & 15, kgrp = lane >> 4;

    // ---- XCD-region mapping: XCD c (= bid&7) owns an 8(M) x 4(N) tile region per
    //      generation; both generations share the same 4 N-tiles (W fetched once
    //      globally). 32 blocks/region == 32 CUs/XCD == co-resident set. ----
    const int bid = blockIdx.x;        // 0..511
    const int xcd = bid & 7;
    const int i_l = bid >> 3;          // 0..63
    const int gen = i_l >> 5;          // 0,1
    const int il  = i_l & 31;          // 0..31
    const int by  = gen * 8 + (il >> 2);   // 0..15
    const int bx  = xcd * 4 + (il & 3);    // 0..31
    const int rowA0 = by * BM;
    const int colB0 = bx * BN;

    // ---- staging addresses: LDS physical o = (q*512+tid)*16 (linear for gload_lds);
    //      logical = o ^ st_16x32 swizzle; decode to (row, colbyte) ----
    const int o0 = tid * 16, o1 = (512 + tid) * 16;
    const int l0 = o0 ^ (((o0 >> 9) & 1) << 5);
    const int l1 = o1 ^ (((o1 >> 9) & 1) << 5);
    const char* gA0 = (const char*)A + ((size_t)(rowA0 + (l0 >> 6)) * KF) * 2 + (l0 & 63);
    const char* gA1 = (const char*)A + ((size_t)(rowA0 + (l1 >> 6)) * KF) * 2 + (l1 & 63);
    const char* gB0 = (const char*)W + ((size_t)(colB0 + (l0 >> 6)) * KF) * 2 + (l0 & 63);
    const char* gB1 = (const char*)W + ((size_t)(colB0 + (l1 >> 6)) * KF) * 2 + (l1 & 63);
    const int ldst0 = wid * 1024;                  // wave-uniform LDS dest, q=0
    const int ldst1 = 8192 + wid * 1024;           // q=1

    // ---- fragment read offsets (swizzled), all later indexing compile-time ----
    int aoff[8], boff[4];
    #pragma unroll
    for (int i = 0; i < 8; ++i) {
        int row = wr * 128 + i * 16 + rlane;
        int o = row * 64 + kgrp * 16;
        aoff[i] = o ^ (((o >> 9) & 1) << 5);
    }
    #pragma unroll
    for (int n = 0; n < 4; ++n) {
        int row = wc * 64 + n * 16 + rlane;
        int o = row * 64 + kgrp * 16;
        boff[n] = o ^ (((o >> 9) & 1) << 5);
    }

#define STAGE_A(j) do { \
    char* b_ = (char*)ldsA + ((j) & 3) * 16384; \
    __builtin_amdgcn_global_load_lds(GLOBAL_P(gA0 + (size_t)(j) * 64), LDS_P(b_ + ldst0), 16, 0, 0); \
    __builtin_amdgcn_global_load_lds(GLOBAL_P(gA1 + (size_t)(j) * 64), LDS_P(b_ + ldst1), 16, 0, 0); \
} while (0)
#define STAGE_B(j) do { \
    char* b_ = (char*)ldsB + ((j) & 3) * 16384; \
    __builtin_amdgcn_global_load_lds(GLOBAL_P(gB0 + (size_t)(j) * 64), LDS_P(b_ + ldst0), 16, 0, 0); \
    __builtin_amdgcn_global_load_lds(GLOBAL_P(gB1 + (size_t)(j) * 64), LDS_P(b_ + ldst1), 16, 0, 0); \
} while (0)
#define LDA(h, slot) do { \
    const char* pa_ = (const char*)ldsA + (slot) * 16384; \
    _Pragma("unroll") for (int mm_ = 0; mm_ < 4; ++mm_) \
        afr[mm_] = *(const short8*)(pa_ + aoff[(h) * 4 + mm_]); \
} while (0)
#define LDB(slot) do { \
    const char* pb_ = (const char*)ldsB + (slot) * 16384; \
    _Pragma("unroll") for (int nn_ = 0; nn_ < 4; ++nn_) \
        bfr[nn_] = *(const short8*)(pb_ + boff[nn_]); \
} while (0)
#define MFMA_HALF(h) do { \
    __builtin_amdgcn_s_setprio(1); \
    _Pragma("unroll") for (int mm_ = 0; mm_ < 4; ++mm_) \
        _Pragma("unroll") for (int nn_ = 0; nn_ < 4; ++nn_) \
            acc[(h) * 4 + mm_][nn_] = __builtin_amdgcn_mfma_f32_16x16x32_bf16( \
                afr[mm_], bfr[nn_], acc[(h) * 4 + mm_][nn_], 0, 0, 0); \
    __builtin_amdgcn_s_setprio(0); \
} while (0)

    f32x4 acc[8][4] = {};
    short8 afr[4], bfr[4];

    // ---- prologue: prime 3 K-half panel pairs (Kh0..Kh2), keep 4 units in flight ----
    STAGE_A(0); STAGE_B(0);
    STAGE_A(1); STAGE_B(1);
    STAGE_A(2); STAGE_B(2);
    WAITVM8();          // Kh0 A,B landed
    BARRIER();

    // ---- main loop: tiles 0..126 (tile 127 peeled) ----
    for (int t = 0; t < NT - 1; ++t) {
        const int j0 = 2 * t;
        const int s0 = j0 & 3, s1 = (j0 + 1) & 3;
        const bool g3 = (j0 + 3) < NKH;
        const bool g4 = (j0 + 4) < NKH;    // false at t==126

        // phase 0: C-half 0 x Kh(j0)
        LDA(0, s0); LDB(s0);
        if (g3) STAGE_A(j0 + 3);
        BARRIER(); WAITLGKM();
        MFMA_HALF(0);
        BARRIER();
        // phase 1: C-half 1 x Kh(j0)
        LDA(1, s0);
        if (g3) STAGE_B(j0 + 3);
        BARRIER(); WAITLGKM();
        MFMA_HALF(1);
        WAITVM8();      // Kh(j0+1) A,B landed
        BARRIER();
        // phase 2: C-half 0 x Kh(j0+1)
        LDA(0, s1); LDB(s1);
        if (g4) STAGE_A(j0 + 4);
        BARRIER(); WAITLGKM();
        MFMA_HALF(0);
        BARRIER();
        // phase 3: C-half 1 x Kh(j0+1)
        LDA(1, s1);
        if (g4) STAGE_B(j0 + 4);
        BARRIER(); WAITLGKM();
        MFMA_HALF(1);
        if (t == NT - 2) { WAITVM4(); } else { WAITVM8(); }   // next tile's Kh pair landed
        BARRIER();
    }

    // ---- peeled last tile (t = 127, j0 = 254, slots 2/3, no stages) ----
    {
        LDA(0, 2); LDB(2);
        BARRIER(); WAITLGKM();
        MFMA_HALF(0);
        BARRIER();
        LDA(1, 2);
        BARRIER(); WAITLGKM();
        MFMA_HALF(1);
        WAITVM0();      // Kh255 landed
        BARRIER();
        LDA(0, 3); LDB(3);
        BARRIER(); WAITLGKM();
        MFMA_HALF(0);
        BARRIER();
        LDA(1, 3);
        WAITLGKM();
        MFMA_HALF(1);
    }

    // ---- epilogue: C/D layout col = lane&15, row = (lane>>4)*4 + r ----
    const float s = *scale_p;
    const int colbase = colB0 + wc * 64 + rlane;
    const int rowbase = rowA0 + wr * 128 + kgrp * 4;
    #pragma unroll
    for (int n = 0; n < 4; ++n) {
        const float bv = bias[colbase + n * 16];
        #pragma unroll
        for (int mf = 0; mf < 8; ++mf) {
            #pragma unroll
            for (int r = 0; r < 4; ++r)
                out[(size_t)(rowbase + mf * 16 + r) * NF + colbase + n * 16] = acc[mf][n][r] * s + bv;
        }
    }
#undef STAGE_A
#undef STAGE_B
#undef LDA
#undef LDB
#undef MFMA_HALF
}

extern "C" void kernel_launch(void* const* d_in, const int* in_sizes, int n_in,
                              void* d_out, int out_size, void* d_ws, size_t ws_size,
                              hipStream_t stream) {
    const float* x      = (const float*)d_in[0];
    const int*   packed = (const int*)d_in[1];
    const int*   signs  = (const int*)d_in[2];
    const float* bias   = (const float*)d_in[3];
    const float* scale  = (const float*)d_in[4];
    const int*   minexp = (const int*)d_in[5];
    float* out = (float*)d_out;

    uint16_t* A = (uint16_t*)d_ws;                                       // 64 MiB
    uint16_t* W = (uint16_t*)((char*)d_ws + (size_t)N_TOK * KF * 2);     // 128 MiB

    quant_x<<<2048, 256, 0, stream>>>(x, scale, A);
    dequant_w<<<2048, 256, 0, stream>>>(packed, signs, minexp, W);
    gemm_bt<<<(N_TOK / BM) * (NF / BN), 512, 0, stream>>>(A, W, bias, scale, out);
}

// Round 4
// 610.416 us; speedup vs baseline: 1.3734x; 1.1104x over previous
//
#include <hip/hip_runtime.h>
#include <hip/hip_bf16.h>
#include <stdint.h>

#define N_TOK 4096   // B*S
#define KF    8192   // IN_F
#define NF    8192   // OUT_F

#define BM 256
#define BN 256
#define NT (KF / 64)    // 128 K-tiles of 64
#define NKH (KF / 32)   // 256 K-half panels of 32

typedef __attribute__((ext_vector_type(8))) short short8;
typedef __attribute__((ext_vector_type(4))) float f32x4;

#define GLOBAL_P(p) ((const __attribute__((address_space(1))) void*)(p))
#define LDS_P(p)    ((__attribute__((address_space(3))) void*)(p))

// ---------- pass 1: int8-quantize activations, store as bf16 (exact) ----------
__global__ void quant_x(const float* __restrict__ x, const float* __restrict__ scale_p,
                        uint16_t* __restrict__ a) {
    const float s = *scale_p;
    const int n8 = N_TOK * KF / 8;
    const int stride = gridDim.x * blockDim.x;
    for (int i = blockIdx.x * blockDim.x + threadIdx.x; i < n8; i += stride) {
        const float4* xp = (const float4*)(x + (size_t)i * 8);
        float4 v0 = xp[0], v1 = xp[1];
        float q[8] = {v0.x, v0.y, v0.z, v0.w, v1.x, v1.y, v1.z, v1.w};
        union { uint16_t u16[8]; short8 v; } o;
        #pragma unroll
        for (int j = 0; j < 8; ++j) {
            float t = rintf(q[j] / s);
            t = fminf(fmaxf(t, -128.f), 127.f);
            union { float f; uint32_t u; } cv; cv.f = t;
            o.u16[j] = (uint16_t)(cv.u >> 16);
        }
        *(short8*)(a + (size_t)i * 8) = o.v;
    }
}

// ---------- pass 2: unpack nibbles + signs -> bf16 weights (exact powers of 2) ----------
__global__ void dequant_w(const int* __restrict__ packed, const int* __restrict__ signs,
                          const int* __restrict__ minexp_p, uint16_t* __restrict__ w) {
    const int me = *minexp_p;
    const int ebase = (me + 127) << 7;
    const int n4 = NF * (KF / 2) / 4;
    const int stride = gridDim.x * blockDim.x;
    for (int i = blockIdx.x * blockDim.x + threadIdx.x; i < n4; i += stride) {
        int4 p  = ((const int4*)packed)[i];
        int4 s0 = ((const int4*)signs)[(size_t)i * 2];
        int4 s1 = ((const int4*)signs)[(size_t)i * 2 + 1];
        int pw[4] = {p.x, p.y, p.z, p.w};
        int sg[8] = {s0.x, s0.y, s0.z, s0.w, s1.x, s1.y, s1.z, s1.w};
        union { uint16_t u16[8]; short8 v; } o;
        #pragma unroll
        for (int j = 0; j < 4; ++j) {
            int lo = pw[j] & 0xF, hi = (pw[j] >> 4) & 0xF;
            o.u16[2 * j]     = (uint16_t)((ebase + (lo << 7)) | (sg[2 * j]     < 0 ? 0x8000 : 0));
            o.u16[2 * j + 1] = (uint16_t)((ebase + (hi << 7)) | (sg[2 * j + 1] < 0 ? 0x8000 : 0));
        }
        *(short8*)(w + (size_t)i * 8) = o.v;
    }
}

// ---------- pass 3: 256x256-tile pipelined 4-phase bf16 GEMM ----------
// out[M,N] = A[M,K] * W[N,K]^T * s + bias
// Frag regs double-buffered one phase ahead; 1 barrier/phase; vmcnt(4) at ph0/ph2.
#define BARRIER()  asm volatile("s_barrier" ::: "memory")
#define WAITVM8()  asm volatile("s_waitcnt vmcnt(8)" ::: "memory")
#define WAITVM4()  asm volatile("s_waitcnt vmcnt(4)" ::: "memory")
#define WAITVM0()  asm volatile("s_waitcnt vmcnt(0)" ::: "memory")
#define SP1 __builtin_amdgcn_s_setprio(1)
#define SP0 __builtin_amdgcn_s_setprio(0)

__global__ __launch_bounds__(512, 2) void gemm_bt(
        const uint16_t* __restrict__ A, const uint16_t* __restrict__ W,
        const float* __restrict__ bias, const float* __restrict__ scale_p,
        float* __restrict__ out) {
    // 4-slot K-half ring per operand: slot = 256 rows x 32 cols bf16 = 16 KiB
    __shared__ uint16_t ldsA[4 * 256 * 32];   // 64 KiB
    __shared__ uint16_t ldsB[4 * 256 * 32];   // 64 KiB

    const int tid  = threadIdx.x;
    const int wid  = tid >> 6, lane = tid & 63;
    const int wr = wid >> 2, wc = wid & 3;         // 2x4 wave grid; wave tile 128x64
    const int rlane = lane & 15, kgrp = lane >> 4;

    // XCD-region mapping (round-3, verified: FETCH 2.1GB -> 453MB)
    const int bid = blockIdx.x;        // 0..511
    const int xcd = bid & 7;
    const int i_l = bid >> 3;          // 0..63
    const int gen = i_l >> 5;          // 0,1
    const int il  = i_l & 31;          // 0..31
    const int by  = gen * 8 + (il >> 2);   // 0..15
    const int bx  = xcd * 4 + (il & 3);    // 0..31
    const int rowA0 = by * BM;
    const int colB0 = bx * BN;

    // staging: LDS physical o = (q*512+tid)*16 linear; global source pre-swizzled (st_16x32)
    const int o0 = tid * 16, o1 = (512 + tid) * 16;
    const int l0 = o0 ^ (((o0 >> 9) & 1) << 5);
    const int l1 = o1 ^ (((o1 >> 9) & 1) << 5);
    const char* gA0 = (const char*)A + ((size_t)(rowA0 + (l0 >> 6)) * KF) * 2 + (l0 & 63);
    const char* gA1 = (const char*)A + ((size_t)(rowA0 + (l1 >> 6)) * KF) * 2 + (l1 & 63);
    const char* gB0 = (const char*)W + ((size_t)(colB0 + (l0 >> 6)) * KF) * 2 + (l0 & 63);
    const char* gB1 = (const char*)W + ((size_t)(colB0 + (l1 >> 6)) * KF) * 2 + (l1 & 63);
    const int ldst0 = wid * 1024;
    const int ldst1 = 8192 + wid * 1024;

    // fragment read offsets (swizzled), compile-time indexed after unroll
    int aoff[8], boff[4];
    #pragma unroll
    for (int i = 0; i < 8; ++i) {
        int row = wr * 128 + i * 16 + rlane;
        int o = row * 64 + kgrp * 16;
        aoff[i] = o ^ (((o >> 9) & 1) << 5);
    }
    #pragma unroll
    for (int n = 0; n < 4; ++n) {
        int row = wc * 64 + n * 16 + rlane;
        int o = row * 64 + kgrp * 16;
        boff[n] = o ^ (((o >> 9) & 1) << 5);
    }

#define STAGE_A(j) do { \
    char* b_ = (char*)ldsA + ((j) & 3) * 16384; \
    __builtin_amdgcn_global_load_lds(GLOBAL_P(gA0 + (size_t)(j) * 64), LDS_P(b_ + ldst0), 16, 0, 0); \
    __builtin_amdgcn_global_load_lds(GLOBAL_P(gA1 + (size_t)(j) * 64), LDS_P(b_ + ldst1), 16, 0, 0); \
} while (0)
#define STAGE_B(j) do { \
    char* b_ = (char*)ldsB + ((j) & 3) * 16384; \
    __builtin_amdgcn_global_load_lds(GLOBAL_P(gB0 + (size_t)(j) * 64), LDS_P(b_ + ldst0), 16, 0, 0); \
    __builtin_amdgcn_global_load_lds(GLOBAL_P(gB1 + (size_t)(j) * 64), LDS_P(b_ + ldst1), 16, 0, 0); \
} while (0)
#define LDA4(DST, H, SLOT) do { \
    const char* p_ = (const char*)ldsA + (SLOT) * 16384; \
    _Pragma("unroll") for (int i_ = 0; i_ < 4; ++i_) \
        DST[i_] = *(const short8*)(p_ + aoff[(H) * 4 + i_]); \
} while (0)
#define LDB4(DST, SLOT) do { \
    const char* p_ = (const char*)ldsB + (SLOT) * 16384; \
    _Pragma("unroll") for (int i_ = 0; i_ < 4; ++i_) \
        DST[i_] = *(const short8*)(p_ + boff[i_]); \
} while (0)
#define MFMA16(H, AF, BF) do { \
    SP1; \
    _Pragma("unroll") for (int mm_ = 0; mm_ < 4; ++mm_) \
        _Pragma("unroll") for (int nn_ = 0; nn_ < 4; ++nn_) \
            acc[(H) * 4 + mm_][nn_] = __builtin_amdgcn_mfma_f32_16x16x32_bf16( \
                AF[mm_], BF[nn_], acc[(H) * 4 + mm_][nn_], 0, 0, 0); \
    SP0; \
} while (0)

// One K-tile = 4 phases. Entering: afrX = A-half0(Kh_s0), bfrE = B(Kh_s0) [issued prev ph3].
// ph0: vmcnt(4) publishes Kh(2t+1) via ph1 barrier; ph2: vmcnt(4) publishes Kh(2t+2) via ph3 barrier.
#define TILE(S0, S1, S0N, ST0, ST1, ST2, ST3, VM0, VM2) do { \
    BARRIER(); VM0; LDA4(afrY, 1, S0);                 ST0; MFMA16(0, afrX, bfrE); \
    BARRIER();      LDA4(afrX, 0, S1); LDB4(bfrO, S1); ST1; MFMA16(1, afrY, bfrE); \
    BARRIER(); VM2; LDA4(afrY, 1, S1);                 ST2; MFMA16(0, afrX, bfrO); \
    BARRIER();      LDA4(afrX, 0, S0N); LDB4(bfrE, S0N); ST3; MFMA16(1, afrY, bfrO); \
} while (0)

    f32x4 acc[8][4] = {};
    short8 afrX[4], afrY[4], bfrE[4], bfrO[4];

    // ---- prologue: stage Kh0..Kh2; land+publish Kh0; issue ph0 frags ----
    STAGE_A(0); STAGE_B(0);
    STAGE_A(1); STAGE_B(1);
    STAGE_A(2); STAGE_B(2);
    WAITVM8();                 // Kh0 A,B landed (own queue)
    BARRIER();                 // publish: all waves' Kh0 loads retired
    LDA4(afrX, 0, 0);
    LDB4(bfrE, 0);

    // ---- main loop: 63 x 2 tiles (t = 0..125) ----
    for (int kt2 = 0; kt2 < 63; ++kt2) {
        const int j0 = kt2 * 4;
        TILE(0, 1, 2,
             STAGE_A(j0 + 3), STAGE_B(j0 + 3), STAGE_A(j0 + 4), STAGE_B(j0 + 4),
             WAITVM4(), WAITVM4());
        TILE(2, 3, 0,
             STAGE_A(j0 + 5), STAGE_B(j0 + 5), STAGE_A(j0 + 6), STAGE_B(j0 + 6),
             WAITVM4(), WAITVM4());
    }

    // ---- t = 126: stages 255 only ----
    TILE(0, 1, 2,
         STAGE_A(255), STAGE_B(255), (void)0, (void)0,
         WAITVM4(), WAITVM4());

    // ---- t = 127 (slots 2,3): no stages, no next-tile reads ----
    BARRIER(); WAITVM0(); LDA4(afrY, 1, 2); MFMA16(0, afrX, bfrE);
    BARRIER(); LDA4(afrX, 0, 3); LDB4(bfrO, 3); MFMA16(1, afrY, bfrE);
    BARRIER(); LDA4(afrY, 1, 3); MFMA16(0, afrX, bfrO);
    BARRIER(); MFMA16(1, afrY, bfrO);

    // ---- epilogue: C/D layout col = lane&15, row = (lane>>4)*4 + r ----
    const float s = *scale_p;
    const int colbase = colB0 + wc * 64 + rlane;
    const int rowbase = rowA0 + wr * 128 + kgrp * 4;
    #pragma unroll
    for (int n = 0; n < 4; ++n) {
        const float bv = bias[colbase + n * 16];
        #pragma unroll
        for (int mf = 0; mf < 8; ++mf) {
            #pragma unroll
            for (int r = 0; r < 4; ++r)
                out[(size_t)(rowbase + mf * 16 + r) * NF + colbase + n * 16] = acc[mf][n][r] * s + bv;
        }
    }
#undef STAGE_A
#undef STAGE_B
#undef LDA4
#undef LDB4
#undef MFMA16
#undef TILE
}

extern "C" void kernel_launch(void* const* d_in, const int* in_sizes, int n_in,
                              void* d_out, int out_size, void* d_ws, size_t ws_size,
                              hipStream_t stream) {
    const float* x      = (const float*)d_in[0];
    const int*   packed = (const int*)d_in[1];
    const int*   signs  = (const int*)d_in[2];
    const float* bias   = (const float*)d_in[3];
    const float* scale  = (const float*)d_in[4];
    const int*   minexp = (const int*)d_in[5];
    float* out = (float*)d_out;

    uint16_t* A = (uint16_t*)d_ws;                                       // 64 MiB
    uint16_t* W = (uint16_t*)((char*)d_ws + (size_t)N_TOK * KF * 2);     // 128 MiB

    quant_x<<<2048, 256, 0, stream>>>(x, scale, A);
    dequant_w<<<2048, 256, 0, stream>>>(packed, signs, minexp, W);
    gemm_bt<<<(N_TOK / BM) * (NF / BN), 512, 0, stream>>>(A, W, bias, scale, out);
}